// Round 1
// baseline (729.745 us; speedup 1.0000x reference)
//
#include <hip/hip_runtime.h>
#include <hip/hip_bf16.h>

// ---------------------------------------------------------------------------
// PLTBlock: out = (x Wq^T)( (x Wk^T)^T (x Wv^T) ) Wp^T + bp + x   (linear attn)
// B=8, S=4096, D=1024.  bf16 MFMA 16x16x32, fp32 accum.
// R4: port the 5 large GEMMs (q,k,v,z,final) to the 256^2-tile 8-phase
//     schedule (T3+T4 counted vmcnt, T5 setprio, rotation swizzle = T2
//     equivalent, raw s_barrier only).  2-deep LDS double buffer (128 KiB),
//     8 waves (2Mx4N), BK=64, 4 phases/K-tile, 2 K-tiles per dbuf cycle.
//     vmcnt(4) at phase 4 (= B(t+2) half-tiles in flight), never 0 in loop.
//     kv GEMM keeps the 128^2 kernel (256^2 grid would be 128 blocks only).
// ---------------------------------------------------------------------------

#define B_DIM 8
#define S_DIM 4096
#define D_DIM 1024
#define M_TOT (B_DIM * S_DIM)   // 32768

using short8 = __attribute__((ext_vector_type(8))) short;
using f32x4  = __attribute__((ext_vector_type(4))) float;

#define TILE_M 128
#define TILE_N 128
#define TILE_K 64

__device__ __forceinline__ void g2l16(const void* g, void* l) {
  __builtin_amdgcn_global_load_lds(
      (const __attribute__((address_space(1))) unsigned int*)g,
      (__attribute__((address_space(3))) unsigned int*)l, 16, 0, 0);
}

__device__ __forceinline__ unsigned short f2b(float f) {
  __hip_bfloat16 h = __float2bfloat16(f);
  return __builtin_bit_cast(unsigned short, h);
}

#define MFMA(d, a, b) d = __builtin_amdgcn_mfma_f32_16x16x32_bf16(a, b, d, 0, 0, 0)

// ===========================================================================
// gemm256: C[m,n] = sum_k A[m,k]*Bt[n,k].  256x256 tile, BK=64, 512 thr,
// 8 waves (wm=wave>>2 in {0,1}, wn=wave&3 in {0..3}), per-wave 128x64 out.
// LDS byte map: buf b at b*65536: A rows 0..255 [0,32768), B rows [32768,65536).
// Rotation swizzle: slot s of row R holds k-chunk (s+R)&7 (16B chunks).
// Phases per K-tile t (compute from buf[t&1]):
//  p1: ds_read A i0-3 (x2 kk) + B j0-1 (x2 kk) =12; stage A(t+1) h0; mfma i0-3 x j0-1
//  p2: ds_read B j2-3 (4);                      stage A(t+1) h1; mfma i0-3 x j2-3
//  p3: ds_read A i4-7 (8);                      stage B(t+2) h0; mfma i4-7 x j0-1
//  p4: no reads;                                stage B(t+2) h1; mfma i4-7 x j2-3
//      vmcnt(4)  (outstanding = B(t+2) h0+h1 = 4 loads -> tile t+1 resident)
// Region-free proof: B reads of buf[cur] end by p2 barrier -> stage B(t+2)@p3/p4
// into cur is safe; A reads of buf[other] (tile t-1) ended by its p3 -> stage
// A(t+1)@p1/p2 into other is safe.
// ===========================================================================
template<bool FINAL>
__global__ __launch_bounds__(512, 2)
void gemm256(const unsigned short* __restrict__ A,
             const unsigned short* __restrict__ Bt,
             void* __restrict__ C,
             int K, int lda, int ldb, int ldc,
             long long sA, long long sB, long long sC,
             const float* __restrict__ bias,
             const float* __restrict__ resid)
{
  __shared__ __align__(16) unsigned short lds[65536];   // 128 KiB
  char* const lb = (char*)lds;

  const int tid  = threadIdx.x;
  const int wave = tid >> 6;
  const int lane = tid & 63;
  const int qd   = lane >> 4;
  const int ln   = lane & 15;
  const int wm   = wave >> 2;
  const int wn   = wave & 3;

  // XCD-stripe swizzle (gridDim.y % 8 == 0 for all our shapes).
  const int flat = blockIdx.y * gridDim.x + blockIdx.x;
  const int strp = flat & 7;
  const int t8   = flat >> 3;
  const int bx   = t8 % gridDim.x;
  const int by   = strp * (gridDim.y >> 3) + t8 / gridDim.x;

  const long long m0 = (long long)by * 256;
  const long long n0 = (long long)bx * 256;
  const int bz = blockIdx.z;
  const unsigned short* Ab = A  + (long long)bz * sA;
  const unsigned short* Bb = Bt + (long long)bz * sB;

  // ---- staging: thread t -> chunk (row tid>>3 in [0,64), slot tid&7),
  // rotated source column g = (slot + row)&7 (row offsets 64/128 are %8==0).
  const int srow = tid >> 3;
  const int scg  = ((tid & 7) + srow) & 7;
  const unsigned short* pA = Ab + (m0 + srow) * lda + scg * 8;
  const unsigned short* pB = Bb + (n0 + srow) * ldb + scg * 8;

  auto stA = [&](int t, int h) {
    const unsigned short* s = pA + t * 64 + h * 128 * lda;
    char* d = lb + (t & 1) * 65536 + h * 16384 + wave * 1024;
    g2l16(s, d);
    g2l16(s + 64 * lda, d + 8192);
  };
  auto stB = [&](int t, int h) {
    const unsigned short* s = pB + t * 64 + h * 128 * ldb;
    char* d = lb + (t & 1) * 65536 + 32768 + h * 16384 + wave * 1024;
    g2l16(s, d);
    g2l16(s + 64 * ldb, d + 8192);
  };

  // ---- fragment reads: row R, chunk g -> byte R*128 + ((g-R)&7)*16.
  // R&7 == ln&7 for every fragment row (bases are %8==0).
  const int co0 = ((qd - ln) & 7) << 4;        // kk=0: g = qd
  const int co1 = ((4 + qd - ln) & 7) << 4;    // kk=1: g = 4+qd
  const int rbA = (wm * 128 + ln) * 128;
  const int rbB = 32768 + (wn * 64 + ln) * 128;

  auto ldA = [&](int cb, int i, int koff) -> short8 {
    return *(const short8*)(lb + cb * 65536 + rbA + i * 2048 + koff);
  };
  auto ldB = [&](int cb, int j, int koff) -> short8 {
    return *(const short8*)(lb + cb * 65536 + rbB + j * 2048 + koff);
  };

  f32x4 acc[8][4];
#pragma unroll
  for (int i = 0; i < 8; ++i)
#pragma unroll
    for (int j = 0; j < 4; ++j)
      acc[i][j] = (f32x4){0.f, 0.f, 0.f, 0.f};

  const int nt = K >> 6;

  // ---- prologue: tile0 complete + B(1).  12 loads; vmcnt(4) -> tile0 landed.
  stA(0, 0); stA(0, 1); stB(0, 0); stB(0, 1);
  stB(1, 0); stB(1, 1);
  asm volatile("s_waitcnt vmcnt(4)" ::: "memory");
  __builtin_amdgcn_s_barrier();

  for (int t = 0; t < nt; ++t) {
    const int cb = t & 1;
    short8 a[4][2], b[4][2];

    // ---------------- phase 1 (12 ds_read)
#pragma unroll
    for (int i = 0; i < 4; ++i) { a[i][0] = ldA(cb, i, co0); a[i][1] = ldA(cb, i, co1); }
#pragma unroll
    for (int j = 0; j < 2; ++j) { b[j][0] = ldB(cb, j, co0); b[j][1] = ldB(cb, j, co1); }
    if (t + 1 < nt) stA(t + 1, 0);
    asm volatile("s_waitcnt lgkmcnt(8)" ::: "memory");
    __builtin_amdgcn_s_barrier();
    asm volatile("s_waitcnt lgkmcnt(0)" ::: "memory");
    __builtin_amdgcn_s_setprio(1);
#pragma unroll
    for (int i = 0; i < 4; ++i)
#pragma unroll
      for (int j = 0; j < 2; ++j) { MFMA(acc[i][j], a[i][0], b[j][0]); MFMA(acc[i][j], a[i][1], b[j][1]); }
    __builtin_amdgcn_s_setprio(0);
    __builtin_amdgcn_s_barrier();

    // ---------------- phase 2 (4 ds_read)
#pragma unroll
    for (int j = 2; j < 4; ++j) { b[j][0] = ldB(cb, j, co0); b[j][1] = ldB(cb, j, co1); }
    if (t + 1 < nt) stA(t + 1, 1);
    __builtin_amdgcn_s_barrier();
    asm volatile("s_waitcnt lgkmcnt(0)" ::: "memory");
    __builtin_amdgcn_s_setprio(1);
#pragma unroll
    for (int i = 0; i < 4; ++i)
#pragma unroll
      for (int j = 2; j < 4; ++j) { MFMA(acc[i][j], a[i][0], b[j][0]); MFMA(acc[i][j], a[i][1], b[j][1]); }
    __builtin_amdgcn_s_setprio(0);
    __builtin_amdgcn_s_barrier();

    // ---------------- phase 3 (8 ds_read)
#pragma unroll
    for (int i = 0; i < 4; ++i) { a[i][0] = ldA(cb, 4 + i, co0); a[i][1] = ldA(cb, 4 + i, co1); }
    if (t + 2 < nt) stB(t + 2, 0);
    __builtin_amdgcn_s_barrier();
    asm volatile("s_waitcnt lgkmcnt(0)" ::: "memory");
    __builtin_amdgcn_s_setprio(1);
#pragma unroll
    for (int i = 0; i < 4; ++i)
#pragma unroll
      for (int j = 0; j < 2; ++j) { MFMA(acc[4 + i][j], a[i][0], b[j][0]); MFMA(acc[4 + i][j], a[i][1], b[j][1]); }
    __builtin_amdgcn_s_setprio(0);
    __builtin_amdgcn_s_barrier();

    // ---------------- phase 4 (0 ds_read) + counted vmcnt
    if (t + 2 < nt) stB(t + 2, 1);
    __builtin_amdgcn_s_barrier();
    __builtin_amdgcn_s_setprio(1);
#pragma unroll
    for (int i = 0; i < 4; ++i)
#pragma unroll
      for (int j = 2; j < 4; ++j) { MFMA(acc[4 + i][j], a[i][0], b[j][0]); MFMA(acc[4 + i][j], a[i][1], b[j][1]); }
    __builtin_amdgcn_s_setprio(0);
    if (t + 2 < nt) { asm volatile("s_waitcnt vmcnt(4)" ::: "memory"); }
    else            { asm volatile("s_waitcnt vmcnt(0)" ::: "memory"); }
    __builtin_amdgcn_s_barrier();
  }

  // ---- epilogue: wave-private LDS restage (16x68 f32, 16B-aligned rows)
  // for full-line coalesced stores.  C/D frag layout: col=ln, row=qd*4+r.
  float* scr = (float*)(lb + wave * 4352);
  const long long crow = m0 + wm * 128;
  const long long ccol = n0 + wn * 64;
  const int er = lane >> 4;          // 0..3
  const int ec = (lane & 15) * 4;    // 0..60

  if constexpr (FINAL) {
    float* Cf = (float*)C + (long long)bz * sC;
#pragma unroll
    for (int i = 0; i < 8; ++i) {
#pragma unroll
      for (int j = 0; j < 4; ++j)
#pragma unroll
        for (int r = 0; r < 4; ++r)
          scr[(qd * 4 + r) * 68 + j * 16 + ln] = acc[i][j][r];
#pragma unroll
      for (int it = 0; it < 4; ++it) {
        const int row = it * 4 + er;
        f32x4 v = *(const f32x4*)(scr + row * 68 + ec);
        const long long gr = crow + i * 16 + row;
        const float4 bb = *(const float4*)(bias + ccol + ec);
        const float4 rr = *(const float4*)(resid + gr * ldc + ccol + ec);
        float4 o;
        o.x = v[0] + bb.x + rr.x; o.y = v[1] + bb.y + rr.y;
        o.z = v[2] + bb.z + rr.z; o.w = v[3] + bb.w + rr.w;
        *(float4*)(Cf + gr * ldc + ccol + ec) = o;
      }
    }
  } else {
    unsigned short* Cb = (unsigned short*)C + (long long)bz * sC;
#pragma unroll
    for (int i = 0; i < 8; ++i) {
#pragma unroll
      for (int j = 0; j < 4; ++j)
#pragma unroll
        for (int r = 0; r < 4; ++r)
          scr[(qd * 4 + r) * 68 + j * 16 + ln] = acc[i][j][r];
#pragma unroll
      for (int it = 0; it < 4; ++it) {
        const int row = it * 4 + er;
        f32x4 v = *(const f32x4*)(scr + row * 68 + ec);
        const long long gr = crow + i * 16 + row;
        ushort4 u;
        u.x = f2b(v[0]); u.y = f2b(v[1]); u.z = f2b(v[2]); u.w = f2b(v[3]);
        *(ushort4*)(Cb + gr * ldc + ccol + ec) = u;
      }
    }
  }
}

// ===========================================================================
// gemm_bt: 128x128 tile (kept for the kv GEMM: M=N=1024 per batch -> 512
// blocks at this tile vs only 128 at 256^2).
// ===========================================================================
template<bool FINAL>
__global__ __launch_bounds__(256, 3)
void gemm_bt(const unsigned short* __restrict__ A,
             const unsigned short* __restrict__ Bt,
             void* __restrict__ C,
             int K, int lda, int ldb, int ldc,
             long long sA, long long sB, long long sC,
             const float* __restrict__ bias,
             const float* __restrict__ resid)
{
  __shared__ __align__(16) unsigned short smem[TILE_M * TILE_K + TILE_N * TILE_K]; // 32 KiB
  unsigned short* As = smem;
  unsigned short* Bs = smem + TILE_M * TILE_K;

  const int tid  = threadIdx.x;
  const int wave = tid >> 6;
  const int lane = tid & 63;
  const int qd   = lane >> 4;
  const int ln   = lane & 15;
  const int wr   = (wave >> 1) * 64;
  const int wc   = (wave & 1) * 64;

  const int flat = blockIdx.y * gridDim.x + blockIdx.x;
  const int strp = flat & 7;
  const int t8   = flat >> 3;
  const int bx   = t8 % gridDim.x;
  const int by   = strp * (gridDim.y >> 3) + t8 / gridDim.x;

  const long long m0 = (long long)by * TILE_M;
  const long long n0 = (long long)bx * TILE_N;
  const int bz = blockIdx.z;

  const unsigned short* Ab = A  + (long long)bz * sA;
  const unsigned short* Bb = Bt + (long long)bz * sB;

  const int srow = tid >> 3;
  const int scg  = ((tid & 7) + (tid >> 3)) & 7;
  const unsigned short* pA = Ab + (m0 + srow) * lda + scg * 8;
  const unsigned short* pB = Bb + (n0 + srow) * ldb + scg * 8;
  const long long rsA = 32LL * lda, rsB = 32LL * ldb;
  unsigned short* lA = As + wave * 512;
  unsigned short* lB = Bs + wave * 512;

  int rowA[4], sA0[4], rowB[4], sB0[4];
#pragma unroll
  for (int i = 0; i < 4; ++i) {
    int ra = wr + i * 16 + ln;
    int rb = wc + i * 16 + ln;
    rowA[i] = ra * 64;  sA0[i] = (qd - ra) & 7;
    rowB[i] = rb * 64;  sB0[i] = (qd - rb) & 7;
  }

  f32x4 acc[4][4];
#pragma unroll
  for (int i = 0; i < 4; ++i)
#pragma unroll
    for (int j = 0; j < 4; ++j)
      acc[i][j] = (f32x4){0.f, 0.f, 0.f, 0.f};

  for (int k0 = 0; k0 < K; k0 += TILE_K) {
#pragma unroll
    for (int it = 0; it < 4; ++it) g2l16(pA + it * rsA, lA + it * 2048);
#pragma unroll
    for (int it = 0; it < 4; ++it) g2l16(pB + it * rsB, lB + it * 2048);
    __syncthreads();

#pragma unroll
    for (int kk = 0; kk < 2; ++kk) {
      short8 af[4], bf[4];
#pragma unroll
      for (int i = 0; i < 4; ++i)
        af[i] = *(const short8*)(As + rowA[i] + (((sA0[i] + kk * 4) & 7) << 3));
#pragma unroll
      for (int j = 0; j < 4; ++j)
        bf[j] = *(const short8*)(Bs + rowB[j] + (((sB0[j] + kk * 4) & 7) << 3));
#pragma unroll
      for (int i = 0; i < 4; ++i)
#pragma unroll
        for (int j = 0; j < 4; ++j)
          acc[i][j] = __builtin_amdgcn_mfma_f32_16x16x32_bf16(af[i], bf[j], acc[i][j], 0, 0, 0);
    }
    __syncthreads();
    pA += TILE_K; pB += TILE_K;
  }

  float* Ct = (float*)smem;
  const int fr = tid >> 3;
  const int fc = (tid & 7) * 4;
  const int hr = tid >> 4;
  const int hc = (tid & 15) * 4;

#pragma unroll
  for (int p = 0; p < 4; ++p) {
    __syncthreads();
    if ((wr >> 6) == (p >> 1)) {
      const int ibase = (p & 1) * 2;
#pragma unroll
      for (int ii = 0; ii < 2; ++ii)
#pragma unroll
        for (int j = 0; j < 4; ++j)
#pragma unroll
          for (int r = 0; r < 4; ++r)
            Ct[(ii * 16 + qd * 4 + r) * 132 + wc + j * 16 + ln] = acc[ibase + ii][j][r];
    }
    __syncthreads();

    if constexpr (FINAL) {
      float* Cf = (float*)C + (long long)bz * sC;
      const long long grow = m0 + p * 32 + fr;
#pragma unroll
      for (int s = 0; s < 4; ++s) {
        const int c = fc + s * 32;
        float4 v = *(const float4*)(Ct + fr * 132 + c);
        const float4 bb = *(const float4*)(bias + n0 + c);
        const float4 rr = *(const float4*)(resid + grow * ldc + n0 + c);
        v.x += bb.x + rr.x; v.y += bb.y + rr.y;
        v.z += bb.z + rr.z; v.w += bb.w + rr.w;
        *(float4*)(Cf + grow * ldc + n0 + c) = v;
      }
    } else {
      unsigned short* Cb = (unsigned short*)C + (long long)bz * sC;
#pragma unroll
      for (int rs = 0; rs < 2; ++rs) {
        const int row = hr + rs * 16;
        const long long grow = m0 + p * 32 + row;
#pragma unroll
        for (int s = 0; s < 2; ++s) {
          const int c = hc + s * 64;
          float4 v = *(const float4*)(Ct + row * 132 + c);
          ushort4 u;
          u.x = f2b(v.x); u.y = f2b(v.y); u.z = f2b(v.z); u.w = f2b(v.w);
          *(ushort4*)(Cb + grow * ldc + n0 + c) = u;
        }
      }
    }
  }
}

// dst[b][e][s] = src[b*S + s][e]
__global__ __launch_bounds__(256)
void transpose_bds(const unsigned short* __restrict__ src,
                   unsigned short* __restrict__ dst)
{
  __shared__ unsigned short tile[64][68];
  const int b  = blockIdx.z;
  const int s0 = blockIdx.x * 64;
  const int e0 = blockIdx.y * 64;
  const int tx = threadIdx.x & 15;
  const int ty = threadIdx.x >> 4;

#pragma unroll
  for (int r = 0; r < 4; ++r) {
    int s = ty * 4 + r;
    ushort4 d = *(const ushort4*)(src + ((size_t)b * S_DIM + s0 + s) * D_DIM + e0 + tx * 4);
    *(ushort4*)&tile[s][tx * 4] = d;
  }
  __syncthreads();
#pragma unroll
  for (int r = 0; r < 4; ++r) {
    int e = ty * 4 + r;
    ushort4 d;
    d.x = tile[tx * 4 + 0][e];
    d.y = tile[tx * 4 + 1][e];
    d.z = tile[tx * 4 + 2][e];
    d.w = tile[tx * 4 + 3][e];
    *(ushort4*)(dst + ((size_t)b * D_DIM + e0 + e) * S_DIM + s0 + tx * 4) = d;
  }
}

__global__ __launch_bounds__(256)
void cast_f32_bf16(const float* __restrict__ src, unsigned short* __restrict__ dst, int n4)
{
  int i = blockIdx.x * 256 + threadIdx.x;
  if (i >= n4) return;
  float4 f = ((const float4*)src)[i];
  ushort4 u;
  u.x = f2b(f.x); u.y = f2b(f.y); u.z = f2b(f.z); u.w = f2b(f.w);
  ((ushort4*)dst)[i] = u;
}

extern "C" void kernel_launch(void* const* d_in, const int* in_sizes, int n_in,
                              void* d_out, int out_size, void* d_ws, size_t ws_size,
                              hipStream_t stream) {
  const float* x  = (const float*)d_in[0];
  const float* Wq = (const float*)d_in[1];
  const float* Wk = (const float*)d_in[2];
  const float* Wv = (const float*)d_in[3];
  const float* Wp = (const float*)d_in[4];
  const float* bp = (const float*)d_in[5];
  float* out = (float*)d_out;
  char* ws = (char*)d_ws;

  unsigned short* xb  = (unsigned short*)(ws + 0);
  unsigned short* Wqb = (unsigned short*)(ws + 67108864);
  unsigned short* Wkb = (unsigned short*)(ws + 69206016);
  unsigned short* Wvb = (unsigned short*)(ws + 71303168);
  unsigned short* Wpb = (unsigned short*)(ws + 73400320);
  unsigned short* qb  = (unsigned short*)(ws + 75497472);
  unsigned short* kb  = (unsigned short*)(ws + 142606336);
  unsigned short* vb  = (unsigned short*)(ws + 209715200);
  unsigned short* kT  = (unsigned short*)(ws + 0);          // reuse xb
  unsigned short* vT  = (unsigned short*)(ws + 142606336);  // reuse kb
  unsigned short* kvT = (unsigned short*)(ws + 209715200);  // reuse vb
  unsigned short* zb  = (unsigned short*)(ws + 0);          // reuse kT

  // ---- casts to bf16 ----
  cast_f32_bf16<<<dim3(M_TOT * D_DIM / 4 / 256), 256, 0, stream>>>(x, xb, M_TOT * D_DIM / 4);
  cast_f32_bf16<<<dim3(D_DIM * D_DIM / 4 / 256), 256, 0, stream>>>(Wq, Wqb, D_DIM * D_DIM / 4);
  cast_f32_bf16<<<dim3(D_DIM * D_DIM / 4 / 256), 256, 0, stream>>>(Wk, Wkb, D_DIM * D_DIM / 4);
  cast_f32_bf16<<<dim3(D_DIM * D_DIM / 4 / 256), 256, 0, stream>>>(Wv, Wvb, D_DIM * D_DIM / 4);
  cast_f32_bf16<<<dim3(D_DIM * D_DIM / 4 / 256), 256, 0, stream>>>(Wp, Wpb, D_DIM * D_DIM / 4);

  // ---- q,k,v = x @ W^T : M=32768, N=1024, K=1024 (256^2 8-phase) ----
  dim3 g256(D_DIM / 256, M_TOT / 256, 1);   // (4,128)
  gemm256<false><<<g256, 512, 0, stream>>>(xb, Wqb, qb, D_DIM, D_DIM, D_DIM, D_DIM, 0, 0, 0, nullptr, nullptr);
  gemm256<false><<<g256, 512, 0, stream>>>(xb, Wkb, kb, D_DIM, D_DIM, D_DIM, D_DIM, 0, 0, 0, nullptr, nullptr);
  gemm256<false><<<g256, 512, 0, stream>>>(xb, Wvb, vb, D_DIM, D_DIM, D_DIM, D_DIM, 0, 0, 0, nullptr, nullptr);

  // ---- kT[b][e][s], vT[b][f][s] ----
  dim3 gt(S_DIM / 64, D_DIM / 64, B_DIM);
  transpose_bds<<<gt, 256, 0, stream>>>(kb, kT);
  transpose_bds<<<gt, 256, 0, stream>>>(vb, vT);

  // ---- kvT[b][f][e] = sum_s vT[f,s] * kT[e,s] : M=N=1024, K=4096 (128^2) ----
  dim3 gkv(D_DIM / TILE_N, D_DIM / TILE_M, B_DIM);
  gemm_bt<false><<<gkv, 256, 0, stream>>>(vT, kT, kvT, S_DIM, S_DIM, S_DIM, D_DIM,
                                          (long long)D_DIM * S_DIM, (long long)D_DIM * S_DIM,
                                          (long long)D_DIM * D_DIM, nullptr, nullptr);

  // ---- z[b][s][f] = sum_e q[s,e] * kvT[f,e] : M=4096, N=1024, K=1024 (256^2) ----
  dim3 gz(D_DIM / 256, S_DIM / 256, B_DIM);  // (4,16,8)
  gemm256<false><<<gz, 512, 0, stream>>>(qb, kvT, zb, D_DIM, D_DIM, D_DIM, D_DIM,
                                         (long long)S_DIM * D_DIM, (long long)D_DIM * D_DIM,
                                         (long long)S_DIM * D_DIM, nullptr, nullptr);

  // ---- out = z @ Wp^T + bp + x : M=32768, N=1024, K=1024, fp32 out (256^2) ----
  gemm256<true><<<g256, 512, 0, stream>>>(zb, Wpb, out, D_DIM, D_DIM, D_DIM, D_DIM,
                                          0, 0, 0, bp, x);
  (void)in_sizes; (void)n_in; (void)out_size; (void)ws_size;
}

// Round 2
// 575.341 us; speedup vs baseline: 1.2684x; 1.2684x over previous
//
#include <hip/hip_runtime.h>
#include <hip/hip_bf16.h>

// ---------------------------------------------------------------------------
// PLTBlock: out = (x Wq^T)( (x Wk^T)^T (x Wv^T) ) Wp^T + bp + x   (linear attn)
// B=8, S=4096, D=1024.  bf16 MFMA 16x16x32, fp32 accum.
// R5: algebraic refactor.  kv = Wk (x^T x) Wv^T and z = x (Wq^T kv), so q,k,v
//     are never materialized.  Pipeline:
//       G  = xT xT^T          (per batch, M=N=1024, K=4096)   68.7 GF
//       H2 = Wv G             (batched 1024^3)                17.2 GF
//       T3 = H2 Wk^T  (=kv^T) (batched 1024^3)                17.2 GF
//       PT = T3 WqT^T (=kv^T Wq) (batched 1024^3)             17.2 GF
//       z  = x PT^T           (M=32768, K=1024)               68.7 GF
//       out= z Wp^T + bp + x  (M=32768, K=1024, fp32 out)     68.7 GF
//     vs old 412 GF / 6 big GEMMs / 2 transposes.  All GEMMs on the proven
//     128^2 3-block/CU kernel (R4's 256^2 8-phase regressed: 1 block/CU made
//     per-phase barriers expose latency; reverted).
// ---------------------------------------------------------------------------

#define B_DIM 8
#define S_DIM 4096
#define D_DIM 1024
#define M_TOT (B_DIM * S_DIM)   // 32768

using short8 = __attribute__((ext_vector_type(8))) short;
using f32x4  = __attribute__((ext_vector_type(4))) float;

#define TILE_M 128
#define TILE_N 128
#define TILE_K 64

__device__ __forceinline__ void g2l16(const void* g, void* l) {
  __builtin_amdgcn_global_load_lds(
      (const __attribute__((address_space(1))) unsigned int*)g,
      (__attribute__((address_space(3))) unsigned int*)l, 16, 0, 0);
}

__device__ __forceinline__ unsigned short f2b(float f) {
  __hip_bfloat16 h = __float2bfloat16(f);
  return __builtin_bit_cast(unsigned short, h);
}

// C[m,n] = sum_k A[m,k] * Bt[n,k]   (A: MxK row-major, Bt: NxK row-major)
// FINAL=false: C bf16.  FINAL=true: C fp32, += bias[n] + resid[m*ldc+n].
// LDS rotation: slot c of row r holds global 16B-chunk (c+r)&7 (conflict-free,
// keeps global_load_lds's wave-uniform-base+lane*16 destination).
template<bool FINAL>
__global__ __launch_bounds__(256, 3)   // 3 waves/EU: arch VGPR+64 AGPR <= 170
void gemm_bt(const unsigned short* __restrict__ A,
             const unsigned short* __restrict__ Bt,
             void* __restrict__ C,
             int K, int lda, int ldb, int ldc,
             long long sA, long long sB, long long sC,
             const float* __restrict__ bias,
             const float* __restrict__ resid)
{
  __shared__ __align__(16) unsigned short smem[TILE_M * TILE_K + TILE_N * TILE_K]; // 32 KiB
  unsigned short* As = smem;
  unsigned short* Bs = smem + TILE_M * TILE_K;

  const int tid  = threadIdx.x;
  const int wave = tid >> 6;
  const int lane = tid & 63;
  const int qd   = lane >> 4;
  const int ln   = lane & 15;
  const int wr   = (wave >> 1) * 64;
  const int wc   = (wave & 1) * 64;

  // XCD-stripe swizzle (xcd ~ flat%8 round-robin).  gridDim.y % 8 == 0 OR
  // gridDim.y == 8 in all our launches -> bijective.
  const int flat = blockIdx.y * gridDim.x + blockIdx.x;
  const int strp = flat & 7;
  const int t8   = flat >> 3;
  const int bx   = t8 % gridDim.x;
  const int by   = strp * (gridDim.y >> 3) + t8 / gridDim.x;

  const long long m0 = (long long)by * TILE_M;
  const long long n0 = (long long)bx * TILE_N;
  const int bz = blockIdx.z;

  const unsigned short* Ab = A  + (long long)bz * sA;
  const unsigned short* Bb = Bt + (long long)bz * sB;

  // Staging: 128x64 bf16 = 16 KiB = 1024 16B-chunks; 256 thr x 4 iters.
  const int srow = tid >> 3;
  const int scg  = ((tid & 7) + (tid >> 3)) & 7;
  const unsigned short* pA = Ab + (m0 + srow) * lda + scg * 8;
  const unsigned short* pB = Bb + (n0 + srow) * ldb + scg * 8;
  const long long rsA = 32LL * lda, rsB = 32LL * ldb;
  unsigned short* lA = As + wave * 512;
  unsigned short* lB = Bs + wave * 512;

  // Fragment row bases + rotation seeds (16 regs; per-kk slot computed inline).
  int rowA[4], sA0[4], rowB[4], sB0[4];
#pragma unroll
  for (int i = 0; i < 4; ++i) {
    int ra = wr + i * 16 + ln;
    int rb = wc + i * 16 + ln;
    rowA[i] = ra * 64;  sA0[i] = (qd - ra) & 7;
    rowB[i] = rb * 64;  sB0[i] = (qd - rb) & 7;
  }

  f32x4 acc[4][4];
#pragma unroll
  for (int i = 0; i < 4; ++i)
#pragma unroll
    for (int j = 0; j < 4; ++j)
      acc[i][j] = (f32x4){0.f, 0.f, 0.f, 0.f};

  for (int k0 = 0; k0 < K; k0 += TILE_K) {
#pragma unroll
    for (int it = 0; it < 4; ++it) g2l16(pA + it * rsA, lA + it * 2048);
#pragma unroll
    for (int it = 0; it < 4; ++it) g2l16(pB + it * rsB, lB + it * 2048);
    __syncthreads();

#pragma unroll
    for (int kk = 0; kk < 2; ++kk) {
      short8 af[4], bf[4];
#pragma unroll
      for (int i = 0; i < 4; ++i)
        af[i] = *(const short8*)(As + rowA[i] + (((sA0[i] + kk * 4) & 7) << 3));
#pragma unroll
      for (int j = 0; j < 4; ++j)
        bf[j] = *(const short8*)(Bs + rowB[j] + (((sB0[j] + kk * 4) & 7) << 3));
#pragma unroll
      for (int i = 0; i < 4; ++i)
#pragma unroll
        for (int j = 0; j < 4; ++j)
          acc[i][j] = __builtin_amdgcn_mfma_f32_16x16x32_bf16(af[i], bf[j], acc[i][j], 0, 0, 0);
    }
    __syncthreads();
    pA += TILE_K; pB += TILE_K;
  }

  // ---- Coalesced epilogue: 4 passes of 32 rows via LDS (stride 132 fp32).
  // acc C/D layout (m89): col = lane&15, row-in-frag = qd*4 + reg.
  float* Ct = (float*)smem;   // 32*132*4 = 16896 B, fits in 32 KiB smem
  const int fr = tid >> 3;            // FINAL: row 0..31
  const int fc = (tid & 7) * 4;       // FINAL: col base; +s*32
  const int hr = tid >> 4;            // bf16: row 0..15 (+rs*16)
  const int hc = (tid & 15) * 4;      // bf16: col base; +s*64

#pragma unroll
  for (int p = 0; p < 4; ++p) {
    __syncthreads();
    if ((wr >> 6) == (p >> 1)) {
      const int ibase = (p & 1) * 2;
#pragma unroll
      for (int ii = 0; ii < 2; ++ii)
#pragma unroll
        for (int j = 0; j < 4; ++j)
#pragma unroll
          for (int r = 0; r < 4; ++r)
            Ct[(ii * 16 + qd * 4 + r) * 132 + wc + j * 16 + ln] = acc[ibase + ii][j][r];
    }
    __syncthreads();

    if constexpr (FINAL) {
      float* Cf = (float*)C + (long long)bz * sC;
      const long long grow = m0 + p * 32 + fr;
#pragma unroll
      for (int s = 0; s < 4; ++s) {
        const int c = fc + s * 32;
        float4 v = *(const float4*)(Ct + fr * 132 + c);
        const float4 bb = *(const float4*)(bias + n0 + c);
        const float4 rr = *(const float4*)(resid + grow * ldc + n0 + c);
        v.x += bb.x + rr.x; v.y += bb.y + rr.y;
        v.z += bb.z + rr.z; v.w += bb.w + rr.w;
        *(float4*)(Cf + grow * ldc + n0 + c) = v;
      }
    } else {
      unsigned short* Cb = (unsigned short*)C + (long long)bz * sC;
#pragma unroll
      for (int rs = 0; rs < 2; ++rs) {
        const int row = hr + rs * 16;
        const long long grow = m0 + p * 32 + row;
#pragma unroll
        for (int s = 0; s < 2; ++s) {
          const int c = hc + s * 64;
          float4 v = *(const float4*)(Ct + row * 132 + c);
          ushort4 u;
          u.x = f2b(v.x); u.y = f2b(v.y); u.z = f2b(v.z); u.w = f2b(v.w);
          *(ushort4*)(Cb + grow * ldc + n0 + c) = u;
        }
      }
    }
  }
}

// dst[b][e][s] = src[b*S + s][e]   (src: [B*S, D] bf16, dst: [B, D, S] bf16)
__global__ __launch_bounds__(256)
void transpose_bds(const unsigned short* __restrict__ src,
                   unsigned short* __restrict__ dst)
{
  __shared__ unsigned short tile[64][68];
  const int b  = blockIdx.z;
  const int s0 = blockIdx.x * 64;
  const int e0 = blockIdx.y * 64;
  const int tx = threadIdx.x & 15;
  const int ty = threadIdx.x >> 4;

#pragma unroll
  for (int r = 0; r < 4; ++r) {
    int s = ty * 4 + r;
    ushort4 d = *(const ushort4*)(src + ((size_t)b * S_DIM + s0 + s) * D_DIM + e0 + tx * 4);
    *(ushort4*)&tile[s][tx * 4] = d;
  }
  __syncthreads();
#pragma unroll
  for (int r = 0; r < 4; ++r) {
    int e = ty * 4 + r;
    ushort4 d;
    d.x = tile[tx * 4 + 0][e];
    d.y = tile[tx * 4 + 1][e];
    d.z = tile[tx * 4 + 2][e];
    d.w = tile[tx * 4 + 3][e];
    *(ushort4*)(dst + ((size_t)b * D_DIM + e0 + e) * S_DIM + s0 + tx * 4) = d;
  }
}

// dst[d][e] = bf16(src[e][d])   (src: 1024x1024 f32, dst: 1024x1024 bf16)
__global__ __launch_bounds__(256)
void cast_transpose_1k(const float* __restrict__ src, unsigned short* __restrict__ dst)
{
  __shared__ unsigned short tile[64][68];
  const int e0 = blockIdx.x * 64;
  const int d0 = blockIdx.y * 64;
  const int tx = threadIdx.x & 15;
  const int ty = threadIdx.x >> 4;

#pragma unroll
  for (int r = 0; r < 4; ++r) {
    int e = ty * 4 + r;
    float4 f = *(const float4*)(src + (size_t)(e0 + e) * D_DIM + d0 + tx * 4);
    ushort4 u;
    u.x = f2b(f.x); u.y = f2b(f.y); u.z = f2b(f.z); u.w = f2b(f.w);
    *(ushort4*)&tile[e][tx * 4] = u;
  }
  __syncthreads();
#pragma unroll
  for (int r = 0; r < 4; ++r) {
    int d = ty * 4 + r;
    ushort4 o;
    o.x = tile[tx * 4 + 0][d];
    o.y = tile[tx * 4 + 1][d];
    o.z = tile[tx * 4 + 2][d];
    o.w = tile[tx * 4 + 3][d];
    *(ushort4*)(dst + (size_t)(d0 + d) * D_DIM + e0 + tx * 4) = o;
  }
}

__global__ __launch_bounds__(256)
void cast_f32_bf16(const float* __restrict__ src, unsigned short* __restrict__ dst, int n4)
{
  int i = blockIdx.x * 256 + threadIdx.x;
  if (i >= n4) return;
  float4 f = ((const float4*)src)[i];
  ushort4 u;
  u.x = f2b(f.x); u.y = f2b(f.y); u.z = f2b(f.z); u.w = f2b(f.w);
  ((ushort4*)dst)[i] = u;
}

extern "C" void kernel_launch(void* const* d_in, const int* in_sizes, int n_in,
                              void* d_out, int out_size, void* d_ws, size_t ws_size,
                              hipStream_t stream) {
  const float* x  = (const float*)d_in[0];
  const float* Wq = (const float*)d_in[1];
  const float* Wk = (const float*)d_in[2];
  const float* Wv = (const float*)d_in[3];
  const float* Wp = (const float*)d_in[4];
  const float* bp = (const float*)d_in[5];
  float* out = (float*)d_out;
  char* ws = (char*)d_ws;

  // Workspace layout (bytes); peak 276824064 (same as previous rounds).
  unsigned short* xb   = (unsigned short*)(ws + 0);          // 64 MB
  unsigned short* Wkb  = (unsigned short*)(ws + 67108864);   // 2 MB
  unsigned short* Wvb  = (unsigned short*)(ws + 69206016);   // 2 MB
  unsigned short* Wpb  = (unsigned short*)(ws + 71303168);   // 2 MB
  unsigned short* WqTb = (unsigned short*)(ws + 73400320);   // 2 MB (Wq^T)
  unsigned short* xT   = (unsigned short*)(ws + 75497472);   // 64 MB [B][D][S]
  unsigned short* G    = (unsigned short*)(ws + 142606336);  // 16 MB [B][1024][1024]
  unsigned short* H2   = (unsigned short*)(ws + 159383552);  // 16 MB
  unsigned short* T3   = (unsigned short*)(ws + 176160768);  // 16 MB
  unsigned short* PT   = (unsigned short*)(ws + 192937984);  // 16 MB
  unsigned short* zb   = (unsigned short*)(ws + 209715200);  // 64 MB

  const long long DD = (long long)D_DIM * D_DIM;
  const long long SD = (long long)S_DIM * D_DIM;

  // ---- casts ----
  cast_f32_bf16<<<dim3(M_TOT * D_DIM / 4 / 256), 256, 0, stream>>>(x, xb, M_TOT * D_DIM / 4);
  cast_f32_bf16<<<dim3(D_DIM * D_DIM / 4 / 256), 256, 0, stream>>>(Wk, Wkb, D_DIM * D_DIM / 4);
  cast_f32_bf16<<<dim3(D_DIM * D_DIM / 4 / 256), 256, 0, stream>>>(Wv, Wvb, D_DIM * D_DIM / 4);
  cast_f32_bf16<<<dim3(D_DIM * D_DIM / 4 / 256), 256, 0, stream>>>(Wp, Wpb, D_DIM * D_DIM / 4);
  cast_transpose_1k<<<dim3(16, 16), 256, 0, stream>>>(Wq, WqTb);

  // ---- xT[b][e][s] = x[b][s][e] ----
  dim3 gt(S_DIM / 64, D_DIM / 64, B_DIM);
  transpose_bds<<<gt, 256, 0, stream>>>(xb, xT);

  // ---- G[b] = x_b^T x_b : C[g,h] = sum_s xT[g,s] xT[h,s].  M=N=1024, K=4096.
  dim3 g1k(D_DIM / TILE_N, D_DIM / TILE_M, B_DIM);   // (8,8,8)
  gemm_bt<false><<<g1k, 256, 0, stream>>>(xT, xT, G, S_DIM, S_DIM, S_DIM, D_DIM,
                                          SD, SD, DD, nullptr, nullptr);

  // ---- H2[b] = Wv G_b  (G symmetric): C[f,g] = sum_k Wv[f,k] G[g,k].
  gemm_bt<false><<<g1k, 256, 0, stream>>>(Wvb, G, H2, D_DIM, D_DIM, D_DIM, D_DIM,
                                          0, DD, DD, nullptr, nullptr);

  // ---- T3[b] = kv^T = H2 Wk^T: C[f,e] = sum_g H2[f,g] Wk[e,g].
  gemm_bt<false><<<g1k, 256, 0, stream>>>(H2, Wkb, T3, D_DIM, D_DIM, D_DIM, D_DIM,
                                          DD, 0, DD, nullptr, nullptr);

  // ---- PT[b] = kv^T Wq: C[f,d] = sum_e T3[f,e] WqT[d,e].
  gemm_bt<false><<<g1k, 256, 0, stream>>>(T3, WqTb, PT, D_DIM, D_DIM, D_DIM, D_DIM,
                                          DD, 0, DD, nullptr, nullptr);

  // ---- z[b] = x_b PT_b^T: C[s,f] = sum_d x[s,d] PT[f,d].  M=4096/batch.
  dim3 gz(D_DIM / TILE_N, S_DIM / TILE_M, B_DIM);    // (8,32,8)
  gemm_bt<false><<<gz, 256, 0, stream>>>(xb, PT, zb, D_DIM, D_DIM, D_DIM, D_DIM,
                                         SD, DD, SD, nullptr, nullptr);

  // ---- out = z Wp^T + bp + x : M=32768, N=1024, K=1024, fp32 out ----
  dim3 gf(D_DIM / TILE_N, M_TOT / TILE_M, 1);        // (8,256,1)
  gemm_bt<true><<<gf, 256, 0, stream>>>(zb, Wpb, out, D_DIM, D_DIM, D_DIM, D_DIM,
                                        0, 0, 0, bp, x);
  (void)in_sizes; (void)n_in; (void)out_size; (void)ws_size;
}

// Round 3
// 520.504 us; speedup vs baseline: 1.4020x; 1.1054x over previous
//
#include <hip/hip_runtime.h>
#include <hip/hip_bf16.h>

// ---------------------------------------------------------------------------
// PLTBlock: out = (x Wq^T)( (x Wk^T)^T (x Wv^T) ) Wp^T + bp + x   (linear attn)
// B=8, S=4096, D=1024.  bf16 MFMA 16x16x32, fp32 accum.
// R6: full algebraic fold.  out = x E + bp + x with
//       E_b = Wq^T Wk G_b Wv^T Wp^T,   G_b = x_b^T x_b   (G symmetric)
//     Compute ET_b = E_b^T = (Wp Wv) G_b (Wk^T Wq) = P1 G_b P2:
//       P1  = Wp Wv          (1024^3, once)         2.1 GF
//       P2T = Wq^T Wk        (1024^3, once)         2.1 GF
//       G   = xT xT^T        (per batch, K=4096)   68.7 GF
//       T   = P1 G_b         (batched 1024^3)      17.2 GF
//       ET  = T P2T^T        (batched 1024^3)      17.2 GF
//       out = x ET^T + bp + x (M=32768, K=1024)    68.7 GF
//     Only TWO big GEMMs remain (G, final) — both touch all of x, irreducible.
//     z is never materialized (removes a 68.7 GF GEMM + 128 MB z traffic).
// ---------------------------------------------------------------------------

#define B_DIM 8
#define S_DIM 4096
#define D_DIM 1024
#define M_TOT (B_DIM * S_DIM)   // 32768

using short8 = __attribute__((ext_vector_type(8))) short;
using f32x4  = __attribute__((ext_vector_type(4))) float;

#define TILE_M 128
#define TILE_N 128
#define TILE_K 64

__device__ __forceinline__ void g2l16(const void* g, void* l) {
  __builtin_amdgcn_global_load_lds(
      (const __attribute__((address_space(1))) unsigned int*)g,
      (__attribute__((address_space(3))) unsigned int*)l, 16, 0, 0);
}

__device__ __forceinline__ unsigned short f2b(float f) {
  __hip_bfloat16 h = __float2bfloat16(f);
  return __builtin_bit_cast(unsigned short, h);
}

// C[m,n] = sum_k A[m,k] * Bt[n,k]   (A: MxK row-major, Bt: NxK row-major)
// FINAL=false: C bf16.  FINAL=true: C fp32, += bias[n] + resid[bz*sC + m*ldc + n].
// LDS rotation: slot c of row r holds global 16B-chunk (c+r)&7 (conflict-free,
// keeps global_load_lds's wave-uniform-base+lane*16 destination).
template<bool FINAL>
__global__ __launch_bounds__(256, 3)   // 3 waves/EU: arch VGPR+64 AGPR <= 170
void gemm_bt(const unsigned short* __restrict__ A,
             const unsigned short* __restrict__ Bt,
             void* __restrict__ C,
             int K, int lda, int ldb, int ldc,
             long long sA, long long sB, long long sC,
             const float* __restrict__ bias,
             const float* __restrict__ resid)
{
  __shared__ __align__(16) unsigned short smem[TILE_M * TILE_K + TILE_N * TILE_K]; // 32 KiB
  unsigned short* As = smem;
  unsigned short* Bs = smem + TILE_M * TILE_K;

  const int tid  = threadIdx.x;
  const int wave = tid >> 6;
  const int lane = tid & 63;
  const int qd   = lane >> 4;
  const int ln   = lane & 15;
  const int wr   = (wave >> 1) * 64;
  const int wc   = (wave & 1) * 64;

  // XCD-stripe swizzle (xcd ~ flat%8 round-robin).  gridDim.y % 8 == 0 in all
  // our launches -> bijective.
  const int flat = blockIdx.y * gridDim.x + blockIdx.x;
  const int strp = flat & 7;
  const int t8   = flat >> 3;
  const int bx   = t8 % gridDim.x;
  const int by   = strp * (gridDim.y >> 3) + t8 / gridDim.x;

  const long long m0 = (long long)by * TILE_M;
  const long long n0 = (long long)bx * TILE_N;
  const int bz = blockIdx.z;

  const unsigned short* Ab = A  + (long long)bz * sA;
  const unsigned short* Bb = Bt + (long long)bz * sB;

  // Staging: 128x64 bf16 = 16 KiB = 1024 16B-chunks; 256 thr x 4 iters.
  const int srow = tid >> 3;
  const int scg  = ((tid & 7) + (tid >> 3)) & 7;
  const unsigned short* pA = Ab + (m0 + srow) * lda + scg * 8;
  const unsigned short* pB = Bb + (n0 + srow) * ldb + scg * 8;
  const long long rsA = 32LL * lda, rsB = 32LL * ldb;
  unsigned short* lA = As + wave * 512;
  unsigned short* lB = Bs + wave * 512;

  // Fragment row bases + rotation seeds (16 regs; per-kk slot computed inline).
  int rowA[4], sA0[4], rowB[4], sB0[4];
#pragma unroll
  for (int i = 0; i < 4; ++i) {
    int ra = wr + i * 16 + ln;
    int rb = wc + i * 16 + ln;
    rowA[i] = ra * 64;  sA0[i] = (qd - ra) & 7;
    rowB[i] = rb * 64;  sB0[i] = (qd - rb) & 7;
  }

  f32x4 acc[4][4];
#pragma unroll
  for (int i = 0; i < 4; ++i)
#pragma unroll
    for (int j = 0; j < 4; ++j)
      acc[i][j] = (f32x4){0.f, 0.f, 0.f, 0.f};

  for (int k0 = 0; k0 < K; k0 += TILE_K) {
#pragma unroll
    for (int it = 0; it < 4; ++it) g2l16(pA + it * rsA, lA + it * 2048);
#pragma unroll
    for (int it = 0; it < 4; ++it) g2l16(pB + it * rsB, lB + it * 2048);
    __syncthreads();

#pragma unroll
    for (int kk = 0; kk < 2; ++kk) {
      short8 af[4], bf[4];
#pragma unroll
      for (int i = 0; i < 4; ++i)
        af[i] = *(const short8*)(As + rowA[i] + (((sA0[i] + kk * 4) & 7) << 3));
#pragma unroll
      for (int j = 0; j < 4; ++j)
        bf[j] = *(const short8*)(Bs + rowB[j] + (((sB0[j] + kk * 4) & 7) << 3));
#pragma unroll
      for (int i = 0; i < 4; ++i)
#pragma unroll
        for (int j = 0; j < 4; ++j)
          acc[i][j] = __builtin_amdgcn_mfma_f32_16x16x32_bf16(af[i], bf[j], acc[i][j], 0, 0, 0);
    }
    __syncthreads();
    pA += TILE_K; pB += TILE_K;
  }

  // ---- Coalesced epilogue: 4 passes of 32 rows via LDS (stride 132 fp32).
  // acc C/D layout (m89): col = lane&15, row-in-frag = qd*4 + reg.
  float* Ct = (float*)smem;   // 32*132*4 = 16896 B, fits in 32 KiB smem
  const int fr = tid >> 3;            // FINAL: row 0..31
  const int fc = (tid & 7) * 4;       // FINAL: col base; +s*32
  const int hr = tid >> 4;            // bf16: row 0..15 (+rs*16)
  const int hc = (tid & 15) * 4;      // bf16: col base; +s*64

#pragma unroll
  for (int p = 0; p < 4; ++p) {
    __syncthreads();
    if ((wr >> 6) == (p >> 1)) {
      const int ibase = (p & 1) * 2;
#pragma unroll
      for (int ii = 0; ii < 2; ++ii)
#pragma unroll
        for (int j = 0; j < 4; ++j)
#pragma unroll
          for (int r = 0; r < 4; ++r)
            Ct[(ii * 16 + qd * 4 + r) * 132 + wc + j * 16 + ln] = acc[ibase + ii][j][r];
    }
    __syncthreads();

    if constexpr (FINAL) {
      float* Cf = (float*)C + (long long)bz * sC;
      const float* Rf = resid + (long long)bz * sC;
      const long long grow = m0 + p * 32 + fr;
#pragma unroll
      for (int s = 0; s < 4; ++s) {
        const int c = fc + s * 32;
        float4 v = *(const float4*)(Ct + fr * 132 + c);
        const float4 bb = *(const float4*)(bias + n0 + c);
        const float4 rr = *(const float4*)(Rf + grow * ldc + n0 + c);
        v.x += bb.x + rr.x; v.y += bb.y + rr.y;
        v.z += bb.z + rr.z; v.w += bb.w + rr.w;
        *(float4*)(Cf + grow * ldc + n0 + c) = v;
      }
    } else {
      unsigned short* Cb = (unsigned short*)C + (long long)bz * sC;
#pragma unroll
      for (int rs = 0; rs < 2; ++rs) {
        const int row = hr + rs * 16;
        const long long grow = m0 + p * 32 + row;
#pragma unroll
        for (int s = 0; s < 2; ++s) {
          const int c = hc + s * 64;
          float4 v = *(const float4*)(Ct + row * 132 + c);
          ushort4 u;
          u.x = f2b(v.x); u.y = f2b(v.y); u.z = f2b(v.z); u.w = f2b(v.w);
          *(ushort4*)(Cb + grow * ldc + n0 + c) = u;
        }
      }
    }
  }
}

// dst[b][e][s] = src[b*S + s][e]   (src: [B*S, D] bf16, dst: [B, D, S] bf16)
__global__ __launch_bounds__(256)
void transpose_bds(const unsigned short* __restrict__ src,
                   unsigned short* __restrict__ dst)
{
  __shared__ unsigned short tile[64][68];
  const int b  = blockIdx.z;
  const int s0 = blockIdx.x * 64;
  const int e0 = blockIdx.y * 64;
  const int tx = threadIdx.x & 15;
  const int ty = threadIdx.x >> 4;

#pragma unroll
  for (int r = 0; r < 4; ++r) {
    int s = ty * 4 + r;
    ushort4 d = *(const ushort4*)(src + ((size_t)b * S_DIM + s0 + s) * D_DIM + e0 + tx * 4);
    *(ushort4*)&tile[s][tx * 4] = d;
  }
  __syncthreads();
#pragma unroll
  for (int r = 0; r < 4; ++r) {
    int e = ty * 4 + r;
    ushort4 d;
    d.x = tile[tx * 4 + 0][e];
    d.y = tile[tx * 4 + 1][e];
    d.z = tile[tx * 4 + 2][e];
    d.w = tile[tx * 4 + 3][e];
    *(ushort4*)(dst + ((size_t)b * D_DIM + e0 + e) * S_DIM + s0 + tx * 4) = d;
  }
}

// dst[d][e] = bf16(src[e][d])   (src: 1024x1024 f32, dst: 1024x1024 bf16)
__global__ __launch_bounds__(256)
void cast_transpose_1k(const float* __restrict__ src, unsigned short* __restrict__ dst)
{
  __shared__ unsigned short tile[64][68];
  const int e0 = blockIdx.x * 64;
  const int d0 = blockIdx.y * 64;
  const int tx = threadIdx.x & 15;
  const int ty = threadIdx.x >> 4;

#pragma unroll
  for (int r = 0; r < 4; ++r) {
    int e = ty * 4 + r;
    float4 f = *(const float4*)(src + (size_t)(e0 + e) * D_DIM + d0 + tx * 4);
    ushort4 u;
    u.x = f2b(f.x); u.y = f2b(f.y); u.z = f2b(f.z); u.w = f2b(f.w);
    *(ushort4*)&tile[e][tx * 4] = u;
  }
  __syncthreads();
#pragma unroll
  for (int r = 0; r < 4; ++r) {
    int d = ty * 4 + r;
    ushort4 o;
    o.x = tile[tx * 4 + 0][d];
    o.y = tile[tx * 4 + 1][d];
    o.z = tile[tx * 4 + 2][d];
    o.w = tile[tx * 4 + 3][d];
    *(ushort4*)(dst + (size_t)(d0 + d) * D_DIM + e0 + tx * 4) = o;
  }
}

__global__ __launch_bounds__(256)
void cast_f32_bf16(const float* __restrict__ src, unsigned short* __restrict__ dst, int n4)
{
  int i = blockIdx.x * 256 + threadIdx.x;
  if (i >= n4) return;
  float4 f = ((const float4*)src)[i];
  ushort4 u;
  u.x = f2b(f.x); u.y = f2b(f.y); u.z = f2b(f.z); u.w = f2b(f.w);
  ((ushort4*)dst)[i] = u;
}

extern "C" void kernel_launch(void* const* d_in, const int* in_sizes, int n_in,
                              void* d_out, int out_size, void* d_ws, size_t ws_size,
                              hipStream_t stream) {
  const float* x  = (const float*)d_in[0];
  const float* Wq = (const float*)d_in[1];
  const float* Wk = (const float*)d_in[2];
  const float* Wv = (const float*)d_in[3];
  const float* Wp = (const float*)d_in[4];
  const float* bp = (const float*)d_in[5];
  float* out = (float*)d_out;
  char* ws = (char*)d_ws;

  // Workspace layout (bytes); peak 197132288.
  unsigned short* xb   = (unsigned short*)(ws + 0);          // 64 MB
  unsigned short* Wpb  = (unsigned short*)(ws + 67108864);   // 2 MB
  unsigned short* WvTb = (unsigned short*)(ws + 69206016);   // 2 MB (Wv^T)
  unsigned short* WqTb = (unsigned short*)(ws + 71303168);   // 2 MB (Wq^T)
  unsigned short* WkTb = (unsigned short*)(ws + 73400320);   // 2 MB (Wk^T)
  unsigned short* P1   = (unsigned short*)(ws + 75497472);   // 2 MB
  unsigned short* P2T  = (unsigned short*)(ws + 77594624);   // 2 MB
  unsigned short* xT   = (unsigned short*)(ws + 79691776);   // 64 MB [B][D][S]
  unsigned short* G    = (unsigned short*)(ws + 146800640);  // 16 MB [B][1024][1024]
  unsigned short* T    = (unsigned short*)(ws + 163577856);  // 16 MB
  unsigned short* ET   = (unsigned short*)(ws + 180355072);  // 16 MB

  const long long DD = (long long)D_DIM * D_DIM;
  const long long SD = (long long)S_DIM * D_DIM;

  // ---- casts ----
  cast_f32_bf16<<<dim3(M_TOT * D_DIM / 4 / 256), 256, 0, stream>>>(x, xb, M_TOT * D_DIM / 4);
  cast_f32_bf16<<<dim3(D_DIM * D_DIM / 4 / 256), 256, 0, stream>>>(Wp, Wpb, D_DIM * D_DIM / 4);
  cast_transpose_1k<<<dim3(16, 16), 256, 0, stream>>>(Wv, WvTb);
  cast_transpose_1k<<<dim3(16, 16), 256, 0, stream>>>(Wq, WqTb);
  cast_transpose_1k<<<dim3(16, 16), 256, 0, stream>>>(Wk, WkTb);

  // ---- xT[b][e][s] = x[b][s][e] ----
  dim3 gt(S_DIM / 64, D_DIM / 64, B_DIM);
  transpose_bds<<<gt, 256, 0, stream>>>(xb, xT);

  // ---- P1 = Wp Wv : C[m,n] = sum_k Wp[m,k] WvT[n,k].  1024^3, once.
  dim3 gw(D_DIM / TILE_N, D_DIM / TILE_M, 1);        // (8,8,1)
  gemm_bt<false><<<gw, 256, 0, stream>>>(Wpb, WvTb, P1, D_DIM, D_DIM, D_DIM, D_DIM,
                                         0, 0, 0, nullptr, nullptr);

  // ---- P2T = Wq^T Wk : C[m,n] = sum_k WqT[m,k] WkT[n,k].  1024^3, once.
  gemm_bt<false><<<gw, 256, 0, stream>>>(WqTb, WkTb, P2T, D_DIM, D_DIM, D_DIM, D_DIM,
                                         0, 0, 0, nullptr, nullptr);

  // ---- G[b] = x_b^T x_b : C[g,h] = sum_s xT[g,s] xT[h,s].  M=N=1024, K=4096.
  dim3 g1k(D_DIM / TILE_N, D_DIM / TILE_M, B_DIM);   // (8,8,8)
  gemm_bt<false><<<g1k, 256, 0, stream>>>(xT, xT, G, S_DIM, S_DIM, S_DIM, D_DIM,
                                          SD, SD, DD, nullptr, nullptr);

  // ---- T[b] = P1 G_b  (G symmetric): C[m,n] = sum_k P1[m,k] G[n,k].
  gemm_bt<false><<<g1k, 256, 0, stream>>>(P1, G, T, D_DIM, D_DIM, D_DIM, D_DIM,
                                          0, DD, DD, nullptr, nullptr);

  // ---- ET[b] = T_b P2 = T_b P2T^T : C[m,n] = sum_k T[m,k] P2T[n,k].
  gemm_bt<false><<<g1k, 256, 0, stream>>>(T, P2T, ET, D_DIM, D_DIM, D_DIM, D_DIM,
                                          DD, 0, DD, nullptr, nullptr);

  // ---- out = x ET^T + bp + x : per batch M=4096, N=1024, K=1024, fp32 out.
  dim3 gf(D_DIM / TILE_N, S_DIM / TILE_M, B_DIM);    // (8,32,8)
  gemm_bt<true><<<gf, 256, 0, stream>>>(xb, ET, out, D_DIM, D_DIM, D_DIM, D_DIM,
                                        SD, DD, SD, bp, x);
  (void)in_sizes; (void)n_in; (void)out_size; (void)ws_size;
}

// Round 4
// 493.417 us; speedup vs baseline: 1.4790x; 1.0549x over previous
//
#include <hip/hip_runtime.h>
#include <hip/hip_bf16.h>

// ---------------------------------------------------------------------------
// PLTBlock: out = (x Wq^T)( (x Wk^T)^T (x Wv^T) ) Wp^T + bp + x   (linear attn)
// B=8, S=4096, D=1024.  bf16 MFMA 16x16x32, fp32 accum.
// R7: structural bundle on top of R6's full algebraic fold
//       out = x (E + I)^T ... wait, out = x E + bp + x = x (E+I) + bp,
//       ET' = (Wp Wv) G (Wk^T Wq) + I = P1 G P2 + I,  G_b = x_b^T x_b.
//     Changes vs R6:
//       * residual folded into ET (+I on diagonal) -> final GEMM loses the
//         128 MB fp32 resid read (FETCH 168 -> ~45 MB predicted).
//       * G computed on upper-triangle 128-tiles only (36/64) + mirror kernel
//         (G symmetric; exact copy) -> G GEMM ~100 -> ~60 us.
//       * x cast + transpose fused (read x f32 once, emit xb and xT).
//       * 3 weight cast-transposes in one launch; P1 & P2T in one batched
//         GEMM launch (ws laid out so z-stride selects operand pair).
//     13 -> 10 launches.
// ---------------------------------------------------------------------------

#define B_DIM 8
#define S_DIM 4096
#define D_DIM 1024
#define M_TOT (B_DIM * S_DIM)   // 32768

using short8 = __attribute__((ext_vector_type(8))) short;
using f32x4  = __attribute__((ext_vector_type(4))) float;

#define TILE_M 128
#define TILE_N 128
#define TILE_K 64

__device__ __forceinline__ void g2l16(const void* g, void* l) {
  __builtin_amdgcn_global_load_lds(
      (const __attribute__((address_space(1))) unsigned int*)g,
      (__attribute__((address_space(3))) unsigned int*)l, 16, 0, 0);
}

__device__ __forceinline__ unsigned short f2b(float f) {
  __hip_bfloat16 h = __float2bfloat16(f);
  return __builtin_bit_cast(unsigned short, h);
}

__device__ __forceinline__ float b2f(unsigned short u) {
  return __bfloat162float(__builtin_bit_cast(__hip_bfloat16, u));
}

// C[m,n] = sum_k A[m,k] * Bt[n,k]   (A: MxK row-major, Bt: NxK row-major)
// FINAL=false: C bf16.  FINAL=true: C fp32, += bias[n]  (residual pre-folded
// into B's diagonal).
// SYMM=true: M==N==1024; grid.x indexes upper-triangle 128-tile pairs
// (by<=bx, 36 of them); batch via grid.z.  Lower tiles mirrored later.
// LDS rotation: slot c of row r holds global 16B-chunk (c+r)&7 (conflict-free,
// keeps global_load_lds's wave-uniform-base+lane*16 destination).
template<bool FINAL, bool SYMM>
__global__ __launch_bounds__(256, 3)   // 3 waves/EU: arch VGPR+64 AGPR <= 170
void gemm_bt(const unsigned short* __restrict__ A,
             const unsigned short* __restrict__ Bt,
             void* __restrict__ C,
             int K, int lda, int ldb, int ldc,
             long long sA, long long sB, long long sC,
             const float* __restrict__ bias)
{
  __shared__ __align__(16) unsigned short smem[TILE_M * TILE_K + TILE_N * TILE_K]; // 32 KiB
  unsigned short* As = smem;
  unsigned short* Bs = smem + TILE_M * TILE_K;

  const int tid  = threadIdx.x;
  const int wave = tid >> 6;
  const int lane = tid & 63;
  const int qd   = lane >> 4;
  const int ln   = lane & 15;
  const int wr   = (wave >> 1) * 64;
  const int wc   = (wave & 1) * 64;

  int bx, by;
  if constexpr (SYMM) {
    // unrank upper-triangle pair (by <= bx) over 8x8 tiles: 36 pairs.
    int r = blockIdx.x, row = 0;
    while (r >= 8 - row) { r -= 8 - row; ++row; }
    by = row; bx = row + r;
  } else {
    // XCD-stripe swizzle (xcd ~ flat%8 round-robin); gridDim.y % 8 == 0.
    const int flat = blockIdx.y * gridDim.x + blockIdx.x;
    const int strp = flat & 7;
    const int t8   = flat >> 3;
    bx = t8 % gridDim.x;
    by = strp * (gridDim.y >> 3) + t8 / gridDim.x;
  }

  const long long m0 = (long long)by * TILE_M;
  const long long n0 = (long long)bx * TILE_N;
  const int bz = blockIdx.z;

  const unsigned short* Ab = A  + (long long)bz * sA;
  const unsigned short* Bb = Bt + (long long)bz * sB;

  // Staging: 128x64 bf16 = 16 KiB = 1024 16B-chunks; 256 thr x 4 iters.
  const int srow = tid >> 3;
  const int scg  = ((tid & 7) + (tid >> 3)) & 7;
  const unsigned short* pA = Ab + (m0 + srow) * lda + scg * 8;
  const unsigned short* pB = Bb + (n0 + srow) * ldb + scg * 8;
  const long long rsA = 32LL * lda, rsB = 32LL * ldb;
  unsigned short* lA = As + wave * 512;
  unsigned short* lB = Bs + wave * 512;

  // Fragment row bases + rotation seeds (16 regs; per-kk slot computed inline).
  int rowA[4], sA0[4], rowB[4], sB0[4];
#pragma unroll
  for (int i = 0; i < 4; ++i) {
    int ra = wr + i * 16 + ln;
    int rb = wc + i * 16 + ln;
    rowA[i] = ra * 64;  sA0[i] = (qd - ra) & 7;
    rowB[i] = rb * 64;  sB0[i] = (qd - rb) & 7;
  }

  f32x4 acc[4][4];
#pragma unroll
  for (int i = 0; i < 4; ++i)
#pragma unroll
    for (int j = 0; j < 4; ++j)
      acc[i][j] = (f32x4){0.f, 0.f, 0.f, 0.f};

  for (int k0 = 0; k0 < K; k0 += TILE_K) {
#pragma unroll
    for (int it = 0; it < 4; ++it) g2l16(pA + it * rsA, lA + it * 2048);
#pragma unroll
    for (int it = 0; it < 4; ++it) g2l16(pB + it * rsB, lB + it * 2048);
    __syncthreads();

#pragma unroll
    for (int kk = 0; kk < 2; ++kk) {
      short8 af[4], bf[4];
#pragma unroll
      for (int i = 0; i < 4; ++i)
        af[i] = *(const short8*)(As + rowA[i] + (((sA0[i] + kk * 4) & 7) << 3));
#pragma unroll
      for (int j = 0; j < 4; ++j)
        bf[j] = *(const short8*)(Bs + rowB[j] + (((sB0[j] + kk * 4) & 7) << 3));
#pragma unroll
      for (int i = 0; i < 4; ++i)
#pragma unroll
        for (int j = 0; j < 4; ++j)
          acc[i][j] = __builtin_amdgcn_mfma_f32_16x16x32_bf16(af[i], bf[j], acc[i][j], 0, 0, 0);
    }
    __syncthreads();
    pA += TILE_K; pB += TILE_K;
  }

  // ---- Coalesced epilogue: 4 passes of 32 rows via LDS (stride 132 fp32).
  // acc C/D layout (m89): col = lane&15, row-in-frag = qd*4 + reg.
  float* Ct = (float*)smem;   // 32*132*4 = 16896 B, fits in 32 KiB smem
  const int fr = tid >> 3;            // FINAL: row 0..31
  const int fc = (tid & 7) * 4;       // FINAL: col base; +s*32
  const int hr = tid >> 4;            // bf16: row 0..15 (+rs*16)
  const int hc = (tid & 15) * 4;      // bf16: col base; +s*64

#pragma unroll
  for (int p = 0; p < 4; ++p) {
    __syncthreads();
    if ((wr >> 6) == (p >> 1)) {
      const int ibase = (p & 1) * 2;
#pragma unroll
      for (int ii = 0; ii < 2; ++ii)
#pragma unroll
        for (int j = 0; j < 4; ++j)
#pragma unroll
          for (int r = 0; r < 4; ++r)
            Ct[(ii * 16 + qd * 4 + r) * 132 + wc + j * 16 + ln] = acc[ibase + ii][j][r];
    }
    __syncthreads();

    if constexpr (FINAL) {
      float* Cf = (float*)C + (long long)bz * sC;
      const long long grow = m0 + p * 32 + fr;
#pragma unroll
      for (int s = 0; s < 4; ++s) {
        const int c = fc + s * 32;
        float4 v = *(const float4*)(Ct + fr * 132 + c);
        const float4 bb = *(const float4*)(bias + n0 + c);
        v.x += bb.x; v.y += bb.y; v.z += bb.z; v.w += bb.w;
        *(float4*)(Cf + grow * ldc + n0 + c) = v;
      }
    } else {
      unsigned short* Cb = (unsigned short*)C + (long long)bz * sC;
#pragma unroll
      for (int rs = 0; rs < 2; ++rs) {
        const int row = hr + rs * 16;
        const long long grow = m0 + p * 32 + row;
#pragma unroll
        for (int s = 0; s < 2; ++s) {
          const int c = hc + s * 64;
          float4 v = *(const float4*)(Ct + row * 132 + c);
          ushort4 u;
          u.x = f2b(v.x); u.y = f2b(v.y); u.z = f2b(v.z); u.w = f2b(v.w);
          *(ushort4*)(Cb + grow * ldc + n0 + c) = u;
        }
      }
    }
  }
}

// Mirror strictly-lower 128-tiles of symmetric G from the computed upper.
// blockIdx.x in [0,28): pair (i>j); blockIdx.y in [0,4): 64x64 sub-block;
// blockIdx.z: batch.  dst[dr, dc] = src[dc, dr].
__global__ __launch_bounds__(256)
void mirror_sym(unsigned short* __restrict__ G)
{
  __shared__ unsigned short tile[64][68];
  int p = blockIdx.x, i = 1;
  while (p >= i) { p -= i; ++i; }
  const int j = p;                       // j < i
  const int dr0 = i * 128 + (blockIdx.y >> 1) * 64;
  const int dc0 = j * 128 + (blockIdx.y & 1) * 64;
  unsigned short* Gb = G + (size_t)blockIdx.z * D_DIM * D_DIM;
  const int tx = threadIdx.x & 15;
  const int ty = threadIdx.x >> 4;

#pragma unroll
  for (int r = 0; r < 4; ++r) {
    int row = ty * 4 + r;                // source row (= dst col range)
    ushort4 d = *(const ushort4*)(Gb + (size_t)(dc0 + row) * D_DIM + dr0 + tx * 4);
    *(ushort4*)&tile[row][tx * 4] = d;
  }
  __syncthreads();
#pragma unroll
  for (int r = 0; r < 4; ++r) {
    int row = ty * 4 + r;                // dst row
    ushort4 d;
    d.x = tile[tx * 4 + 0][row];
    d.y = tile[tx * 4 + 1][row];
    d.z = tile[tx * 4 + 2][row];
    d.w = tile[tx * 4 + 3][row];
    *(ushort4*)(Gb + (size_t)(dr0 + row) * D_DIM + dc0 + tx * 4) = d;
  }
}

// ET[b][d][d] += 1.0  (residual fold: out = x (E+I) + bp)
__global__ __launch_bounds__(256)
void add_eye(unsigned short* __restrict__ ET)
{
  const int d = blockIdx.x * 256 + threadIdx.x;
  const size_t idx = (size_t)blockIdx.y * D_DIM * D_DIM + (size_t)d * D_DIM + d;
  ET[idx] = f2b(b2f(ET[idx]) + 1.0f);
}

// Fused: xb[b*S+s][e] = bf16(x[b][s][e]);  xT[b][e][s] = same value.
__global__ __launch_bounds__(256)
void cast_transpose_x(const float* __restrict__ x,
                      unsigned short* __restrict__ xb,
                      unsigned short* __restrict__ xT)
{
  __shared__ unsigned short tile[64][68];
  const int b  = blockIdx.z;
  const int s0 = blockIdx.x * 64;
  const int e0 = blockIdx.y * 64;
  const int tx = threadIdx.x & 15;
  const int ty = threadIdx.x >> 4;

#pragma unroll
  for (int r = 0; r < 4; ++r) {
    int s = ty * 4 + r;
    const size_t off = ((size_t)b * S_DIM + s0 + s) * D_DIM + e0 + tx * 4;
    float4 f = *(const float4*)(x + off);
    ushort4 u;
    u.x = f2b(f.x); u.y = f2b(f.y); u.z = f2b(f.z); u.w = f2b(f.w);
    *(ushort4*)&tile[s][tx * 4] = u;
    *(ushort4*)(xb + off) = u;
  }
  __syncthreads();
#pragma unroll
  for (int r = 0; r < 4; ++r) {
    int e = ty * 4 + r;
    ushort4 d;
    d.x = tile[tx * 4 + 0][e];
    d.y = tile[tx * 4 + 1][e];
    d.z = tile[tx * 4 + 2][e];
    d.w = tile[tx * 4 + 3][e];
    *(ushort4*)(xT + ((size_t)b * D_DIM + e0 + e) * S_DIM + s0 + tx * 4) = d;
  }
}

// Three 1024x1024 cast+transpose in one launch: z selects (Wq,Wk,Wv).
// dst[d][e] = bf16(src[e][d]).
__global__ __launch_bounds__(256)
void cast_transpose_w(const float* __restrict__ Wq, const float* __restrict__ Wk,
                      const float* __restrict__ Wv,
                      unsigned short* __restrict__ WqT, unsigned short* __restrict__ WkT,
                      unsigned short* __restrict__ WvT)
{
  __shared__ unsigned short tile[64][68];
  const int z = blockIdx.z;
  const float* src = (z == 0) ? Wq : (z == 1) ? Wk : Wv;
  unsigned short* dst = (z == 0) ? WqT : (z == 1) ? WkT : WvT;
  const int e0 = blockIdx.x * 64;
  const int d0 = blockIdx.y * 64;
  const int tx = threadIdx.x & 15;
  const int ty = threadIdx.x >> 4;

#pragma unroll
  for (int r = 0; r < 4; ++r) {
    int e = ty * 4 + r;
    float4 f = *(const float4*)(src + (size_t)(e0 + e) * D_DIM + d0 + tx * 4);
    ushort4 u;
    u.x = f2b(f.x); u.y = f2b(f.y); u.z = f2b(f.z); u.w = f2b(f.w);
    *(ushort4*)&tile[e][tx * 4] = u;
  }
  __syncthreads();
#pragma unroll
  for (int r = 0; r < 4; ++r) {
    int d = ty * 4 + r;
    ushort4 o;
    o.x = tile[tx * 4 + 0][d];
    o.y = tile[tx * 4 + 1][d];
    o.z = tile[tx * 4 + 2][d];
    o.w = tile[tx * 4 + 3][d];
    *(ushort4*)(dst + (size_t)(d0 + d) * D_DIM + e0 + tx * 4) = o;
  }
}

__global__ __launch_bounds__(256)
void cast_f32_bf16(const float* __restrict__ src, unsigned short* __restrict__ dst, int n4)
{
  int i = blockIdx.x * 256 + threadIdx.x;
  if (i >= n4) return;
  float4 f = ((const float4*)src)[i];
  ushort4 u;
  u.x = f2b(f.x); u.y = f2b(f.y); u.z = f2b(f.z); u.w = f2b(f.w);
  ((ushort4*)dst)[i] = u;
}

extern "C" void kernel_launch(void* const* d_in, const int* in_sizes, int n_in,
                              void* d_out, int out_size, void* d_ws, size_t ws_size,
                              hipStream_t stream) {
  const float* x  = (const float*)d_in[0];
  const float* Wq = (const float*)d_in[1];
  const float* Wk = (const float*)d_in[2];
  const float* Wv = (const float*)d_in[3];
  const float* Wp = (const float*)d_in[4];
  const float* bp = (const float*)d_in[5];
  float* out = (float*)d_out;
  char* ws = (char*)d_ws;

  // Workspace layout (bytes); peak 197132288.
  // Order matters: (Wpb,WqTb) and (WvTb,WkTb) and (P1,P2T) are consecutive
  // 2 MB pairs so one batched GEMM launch (z-stride DD) computes P1 and P2T.
  unsigned short* xb   = (unsigned short*)(ws + 0);          // 64 MB
  unsigned short* Wpb  = (unsigned short*)(ws + 67108864);   // 2 MB  (A, z=0)
  unsigned short* WqTb = (unsigned short*)(ws + 69206016);   // 2 MB  (A, z=1)
  unsigned short* WvTb = (unsigned short*)(ws + 71303168);   // 2 MB  (B, z=0)
  unsigned short* WkTb = (unsigned short*)(ws + 73400320);   // 2 MB  (B, z=1)
  unsigned short* P1   = (unsigned short*)(ws + 75497472);   // 2 MB  (C, z=0)
  unsigned short* P2T  = (unsigned short*)(ws + 77594624);   // 2 MB  (C, z=1)
  unsigned short* xT   = (unsigned short*)(ws + 79691776);   // 64 MB [B][D][S]
  unsigned short* G    = (unsigned short*)(ws + 146800640);  // 16 MB [B][1024][1024]
  unsigned short* T    = (unsigned short*)(ws + 163577856);  // 16 MB
  unsigned short* ET   = (unsigned short*)(ws + 180355072);  // 16 MB

  const long long DD = (long long)D_DIM * D_DIM;
  const long long SD = (long long)S_DIM * D_DIM;

  // ---- x: cast + transpose fused (read f32 once) ----
  dim3 gx(S_DIM / 64, D_DIM / 64, B_DIM);
  cast_transpose_x<<<gx, 256, 0, stream>>>(x, xb, xT);

  // ---- weights: Wp plain cast; Wq/Wk/Wv cast+transpose in one launch ----
  cast_f32_bf16<<<dim3(D_DIM * D_DIM / 4 / 256), 256, 0, stream>>>(Wp, Wpb, D_DIM * D_DIM / 4);
  cast_transpose_w<<<dim3(16, 16, 3), 256, 0, stream>>>(Wq, Wk, Wv, WqTb, WkTb, WvTb);

  // ---- P1 = Wp Wv, P2T = Wq^T Wk : one batched launch (z in {0,1}) ----
  dim3 gw(D_DIM / TILE_N, D_DIM / TILE_M, 2);        // (8,8,2)
  gemm_bt<false, false><<<gw, 256, 0, stream>>>(Wpb, WvTb, P1, D_DIM, D_DIM, D_DIM, D_DIM,
                                                DD, DD, DD, nullptr);

  // ---- G[b] = x_b^T x_b : upper-triangle 128-tiles only (36), then mirror.
  gemm_bt<false, true><<<dim3(36, 1, B_DIM), 256, 0, stream>>>(
      xT, xT, G, S_DIM, S_DIM, S_DIM, D_DIM, SD, SD, DD, nullptr);
  mirror_sym<<<dim3(28, 4, B_DIM), 256, 0, stream>>>(G);

  // ---- T[b] = P1 G_b  (G symmetric): C[m,n] = sum_k P1[m,k] G[n,k].
  dim3 g1k(D_DIM / TILE_N, D_DIM / TILE_M, B_DIM);   // (8,8,8)
  gemm_bt<false, false><<<g1k, 256, 0, stream>>>(P1, G, T, D_DIM, D_DIM, D_DIM, D_DIM,
                                                 0, DD, DD, nullptr);

  // ---- ET[b] = T_b P2 = T_b P2T^T : C[m,n] = sum_k T[m,k] P2T[n,k].
  gemm_bt<false, false><<<g1k, 256, 0, stream>>>(T, P2T, ET, D_DIM, D_DIM, D_DIM, D_DIM,
                                                 DD, 0, DD, nullptr);

  // ---- ET += I  (residual fold) ----
  add_eye<<<dim3(D_DIM / 256, B_DIM), 256, 0, stream>>>(ET);

  // ---- out = x (E+I)^T + bp : per batch M=4096, N=1024, K=1024, fp32 out.
  dim3 gf(D_DIM / TILE_N, S_DIM / TILE_M, B_DIM);    // (8,32,8)
  gemm_bt<true, false><<<gf, 256, 0, stream>>>(xb, ET, out, D_DIM, D_DIM, D_DIM, D_DIM,
                                               SD, DD, SD, bp);
  (void)in_sizes; (void)n_in; (void)out_size; (void)ws_size;
}

// Round 5
// 488.735 us; speedup vs baseline: 1.4931x; 1.0096x over previous
//
#include <hip/hip_runtime.h>
#include <hip/hip_bf16.h>

// ---------------------------------------------------------------------------
// PLTBlock: out = (x Wq^T)( (x Wk^T)^T (x Wv^T) ) Wp^T + bp + x   (linear attn)
// B=8, S=4096, D=1024.  bf16 MFMA 16x16x32, fp32 accum.
// R8: occupancy + fusion bundle on top of R7's algebra
//       out = x (E+I) + bp,  ET = (Wp Wv) G (Wk^T Wq) + I,  G_b = x_b^T x_b.
//     * __launch_bounds__(256,4): 64 arch VGPR + 64 AGPR = 128 = 512/4 ->
//       4 blocks/CU co-resident (was 3) to hide the per-K-step vmcnt(0)+
//       barrier drain (final GEMM is latency-bound at 31% HBM, 31% MFMA).
//     * G-symm epilogue writes BOTH triangles (mirror kernel removed).
//     * +I folded into ET GEMM epilogue (add_eye removed).
//     * Wp cast folded into the weight cast+transpose launch (z=3).
//     10 -> 7 launches.
// ---------------------------------------------------------------------------

#define B_DIM 8
#define S_DIM 4096
#define D_DIM 1024
#define M_TOT (B_DIM * S_DIM)   // 32768

using short8 = __attribute__((ext_vector_type(8))) short;
using f32x4  = __attribute__((ext_vector_type(4))) float;

#define TILE_M 128
#define TILE_N 128
#define TILE_K 64

__device__ __forceinline__ void g2l16(const void* g, void* l) {
  __builtin_amdgcn_global_load_lds(
      (const __attribute__((address_space(1))) unsigned int*)g,
      (__attribute__((address_space(3))) unsigned int*)l, 16, 0, 0);
}

__device__ __forceinline__ unsigned short f2b(float f) {
  __hip_bfloat16 h = __float2bfloat16(f);
  return __builtin_bit_cast(unsigned short, h);
}

// C[m,n] = sum_k A[m,k] * Bt[n,k]   (A: MxK row-major, Bt: NxK row-major)
// FINAL=false: C bf16.  FINAL=true: C fp32, += bias[n] (residual pre-folded).
// SYMM=true: M==N==1024; grid.x indexes upper-triangle 128-tile pairs
// (by<=bx, 36); epilogue writes the mirrored lower tile too (C symmetric).
// ADDI=true: C[m,n] += (m==n)  (identity fold for the residual).
// LDS rotation: slot c of row r holds global 16B-chunk (c+r)&7 (conflict-free,
// keeps global_load_lds's wave-uniform-base+lane*16 destination).
template<bool FINAL, bool SYMM, bool ADDI>
__global__ __launch_bounds__(256, 4)   // 4 blocks/CU: 64 arch VGPR + 64 AGPR = 128
void gemm_bt(const unsigned short* __restrict__ A,
             const unsigned short* __restrict__ Bt,
             void* __restrict__ C,
             int K, int lda, int ldb, int ldc,
             long long sA, long long sB, long long sC,
             const float* __restrict__ bias)
{
  __shared__ __align__(16) unsigned short smem[TILE_M * TILE_K + TILE_N * TILE_K]; // 32 KiB
  unsigned short* As = smem;
  unsigned short* Bs = smem + TILE_M * TILE_K;

  const int tid  = threadIdx.x;
  const int wave = tid >> 6;
  const int lane = tid & 63;
  const int qd   = lane >> 4;
  const int ln   = lane & 15;
  const int wr   = (wave >> 1) * 64;
  const int wc   = (wave & 1) * 64;

  int bx, by;
  if constexpr (SYMM) {
    // unrank upper-triangle pair (by <= bx) over 8x8 tiles: 36 pairs.
    int r = blockIdx.x, row = 0;
    while (r >= 8 - row) { r -= 8 - row; ++row; }
    by = row; bx = row + r;
  } else {
    // XCD-stripe swizzle (xcd ~ flat%8 round-robin); gridDim.y % 8 == 0.
    const int flat = blockIdx.y * gridDim.x + blockIdx.x;
    const int strp = flat & 7;
    const int t8   = flat >> 3;
    bx = t8 % gridDim.x;
    by = strp * (gridDim.y >> 3) + t8 / gridDim.x;
  }

  const long long m0 = (long long)by * TILE_M;
  const long long n0 = (long long)bx * TILE_N;
  const int bz = blockIdx.z;

  const unsigned short* Ab = A  + (long long)bz * sA;
  const unsigned short* Bb = Bt + (long long)bz * sB;

  // Staging: 128x64 bf16 = 16 KiB = 1024 16B-chunks; 256 thr x 4 iters.
  const int srow = tid >> 3;
  const int scg  = ((tid & 7) + (tid >> 3)) & 7;
  const unsigned short* pA = Ab + (m0 + srow) * lda + scg * 8;
  const unsigned short* pB = Bb + (n0 + srow) * ldb + scg * 8;
  const long long rsA = 32LL * lda, rsB = 32LL * ldb;
  unsigned short* lA = As + wave * 512;
  unsigned short* lB = Bs + wave * 512;

  // Fragment row bases + rotation seeds (16 regs; per-kk slot computed inline).
  int rowA[4], sA0[4], rowB[4], sB0[4];
#pragma unroll
  for (int i = 0; i < 4; ++i) {
    int ra = wr + i * 16 + ln;
    int rb = wc + i * 16 + ln;
    rowA[i] = ra * 64;  sA0[i] = (qd - ra) & 7;
    rowB[i] = rb * 64;  sB0[i] = (qd - rb) & 7;
  }

  f32x4 acc[4][4];
#pragma unroll
  for (int i = 0; i < 4; ++i)
#pragma unroll
    for (int j = 0; j < 4; ++j)
      acc[i][j] = (f32x4){0.f, 0.f, 0.f, 0.f};

  for (int k0 = 0; k0 < K; k0 += TILE_K) {
#pragma unroll
    for (int it = 0; it < 4; ++it) g2l16(pA + it * rsA, lA + it * 2048);
#pragma unroll
    for (int it = 0; it < 4; ++it) g2l16(pB + it * rsB, lB + it * 2048);
    __syncthreads();

#pragma unroll
    for (int kk = 0; kk < 2; ++kk) {
      short8 af[4], bf[4];
#pragma unroll
      for (int i = 0; i < 4; ++i)
        af[i] = *(const short8*)(As + rowA[i] + (((sA0[i] + kk * 4) & 7) << 3));
#pragma unroll
      for (int j = 0; j < 4; ++j)
        bf[j] = *(const short8*)(Bs + rowB[j] + (((sB0[j] + kk * 4) & 7) << 3));
#pragma unroll
      for (int i = 0; i < 4; ++i)
#pragma unroll
        for (int j = 0; j < 4; ++j)
          acc[i][j] = __builtin_amdgcn_mfma_f32_16x16x32_bf16(af[i], bf[j], acc[i][j], 0, 0, 0);
    }
    __syncthreads();
    pA += TILE_K; pB += TILE_K;
  }

  // ---- Coalesced epilogue: 4 passes of 32 rows via LDS (stride 132 fp32).
  // acc C/D layout (m89): col = lane&15, row-in-frag = qd*4 + reg.
  float* Ct = (float*)smem;   // 32*132*4 = 16896 B, fits in 32 KiB smem
  const int fr = tid >> 3;            // FINAL: row 0..31
  const int fc = (tid & 7) * 4;       // FINAL: col base; +s*32
  const int hr = tid >> 4;            // bf16: row 0..15 (+rs*16)
  const int hc = (tid & 15) * 4;      // bf16: col base; +s*64

#pragma unroll
  for (int p = 0; p < 4; ++p) {
    __syncthreads();
    if ((wr >> 6) == (p >> 1)) {
      const int ibase = (p & 1) * 2;
#pragma unroll
      for (int ii = 0; ii < 2; ++ii)
#pragma unroll
        for (int j = 0; j < 4; ++j)
#pragma unroll
          for (int r = 0; r < 4; ++r)
            Ct[(ii * 16 + qd * 4 + r) * 132 + wc + j * 16 + ln] = acc[ibase + ii][j][r];
    }
    __syncthreads();

    if constexpr (FINAL) {
      float* Cf = (float*)C + (long long)bz * sC;
      const long long grow = m0 + p * 32 + fr;
#pragma unroll
      for (int s = 0; s < 4; ++s) {
        const int c = fc + s * 32;
        float4 v = *(const float4*)(Ct + fr * 132 + c);
        const float4 bb = *(const float4*)(bias + n0 + c);
        v.x += bb.x; v.y += bb.y; v.z += bb.z; v.w += bb.w;
        *(float4*)(Cf + grow * ldc + n0 + c) = v;
      }
    } else {
      unsigned short* Cb = (unsigned short*)C + (long long)bz * sC;
#pragma unroll
      for (int rs = 0; rs < 2; ++rs) {
        const int row = hr + rs * 16;
        const long long grow = m0 + p * 32 + row;
#pragma unroll
        for (int s = 0; s < 2; ++s) {
          const int c = hc + s * 64;
          float4 v = *(const float4*)(Ct + row * 132 + c);
          if constexpr (ADDI) {
            const int dj = (int)(grow - (n0 + c));   // diagonal hit if 0..3
            if (dj == 0) v.x += 1.0f;
            else if (dj == 1) v.y += 1.0f;
            else if (dj == 2) v.z += 1.0f;
            else if (dj == 3) v.w += 1.0f;
          }
          ushort4 u;
          u.x = f2b(v.x); u.y = f2b(v.y); u.z = f2b(v.z); u.w = f2b(v.w);
          *(ushort4*)(Cb + grow * ldc + n0 + c) = u;
        }
      }
      if constexpr (SYMM) {
        // Mirror: C[n0+col][m0+p*32+row'] = slab[row'][col].  256 thr cover
        // 128 cols x 2 sixteen-wide row-chunks.
        if (m0 != n0) {
          const int mr = tid >> 1;           // source col = dst row offset
          const int mc = (tid & 1) * 16;     // source row base
          const long long trow = n0 + mr;
          const long long tcol = m0 + p * 32 + mc;
#pragma unroll
          for (int jj = 0; jj < 4; ++jj) {
            ushort4 u;
            u.x = f2b(Ct[(mc + jj * 4 + 0) * 132 + mr]);
            u.y = f2b(Ct[(mc + jj * 4 + 1) * 132 + mr]);
            u.z = f2b(Ct[(mc + jj * 4 + 2) * 132 + mr]);
            u.w = f2b(Ct[(mc + jj * 4 + 3) * 132 + mr]);
            *(ushort4*)(Cb + trow * ldc + tcol + jj * 4) = u;
          }
        }
      }
    }
  }
}

// Fused: xb[b*S+s][e] = bf16(x[b][s][e]);  xT[b][e][s] = same value.
__global__ __launch_bounds__(256)
void cast_transpose_x(const float* __restrict__ x,
                      unsigned short* __restrict__ xb,
                      unsigned short* __restrict__ xT)
{
  __shared__ unsigned short tile[64][68];
  const int b  = blockIdx.z;
  const int s0 = blockIdx.x * 64;
  const int e0 = blockIdx.y * 64;
  const int tx = threadIdx.x & 15;
  const int ty = threadIdx.x >> 4;

#pragma unroll
  for (int r = 0; r < 4; ++r) {
    int s = ty * 4 + r;
    const size_t off = ((size_t)b * S_DIM + s0 + s) * D_DIM + e0 + tx * 4;
    float4 f = *(const float4*)(x + off);
    ushort4 u;
    u.x = f2b(f.x); u.y = f2b(f.y); u.z = f2b(f.z); u.w = f2b(f.w);
    *(ushort4*)&tile[s][tx * 4] = u;
    *(ushort4*)(xb + off) = u;
  }
  __syncthreads();
#pragma unroll
  for (int r = 0; r < 4; ++r) {
    int e = ty * 4 + r;
    ushort4 d;
    d.x = tile[tx * 4 + 0][e];
    d.y = tile[tx * 4 + 1][e];
    d.z = tile[tx * 4 + 2][e];
    d.w = tile[tx * 4 + 3][e];
    *(ushort4*)(xT + ((size_t)b * D_DIM + e0 + e) * S_DIM + s0 + tx * 4) = d;
  }
}

// Weight prep, one launch.  z in {0,1,2}: dst[d][e] = bf16(src[e][d])
// (cast+transpose for Wq,Wk,Wv).  z==3: plain cast Wp -> Wpb.
__global__ __launch_bounds__(256)
void prep_w(const float* __restrict__ Wq, const float* __restrict__ Wk,
            const float* __restrict__ Wv, const float* __restrict__ Wp,
            unsigned short* __restrict__ WqT, unsigned short* __restrict__ WkT,
            unsigned short* __restrict__ WvT, unsigned short* __restrict__ Wpb)
{
  __shared__ unsigned short tile[64][68];
  const int z = blockIdx.z;
  const int e0 = blockIdx.x * 64;
  const int d0 = blockIdx.y * 64;
  const int tx = threadIdx.x & 15;
  const int ty = threadIdx.x >> 4;

  if (z == 3) {   // plain cast
#pragma unroll
    for (int r = 0; r < 4; ++r) {
      int e = ty * 4 + r;
      const size_t off = (size_t)(e0 + e) * D_DIM + d0 + tx * 4;
      float4 f = *(const float4*)(Wp + off);
      ushort4 u;
      u.x = f2b(f.x); u.y = f2b(f.y); u.z = f2b(f.z); u.w = f2b(f.w);
      *(ushort4*)(Wpb + off) = u;
    }
    return;
  }

  const float* src = (z == 0) ? Wq : (z == 1) ? Wk : Wv;
  unsigned short* dst = (z == 0) ? WqT : (z == 1) ? WkT : WvT;

#pragma unroll
  for (int r = 0; r < 4; ++r) {
    int e = ty * 4 + r;
    float4 f = *(const float4*)(src + (size_t)(e0 + e) * D_DIM + d0 + tx * 4);
    ushort4 u;
    u.x = f2b(f.x); u.y = f2b(f.y); u.z = f2b(f.z); u.w = f2b(f.w);
    *(ushort4*)&tile[e][tx * 4] = u;
  }
  __syncthreads();
#pragma unroll
  for (int r = 0; r < 4; ++r) {
    int d = ty * 4 + r;
    ushort4 o;
    o.x = tile[tx * 4 + 0][d];
    o.y = tile[tx * 4 + 1][d];
    o.z = tile[tx * 4 + 2][d];
    o.w = tile[tx * 4 + 3][d];
    *(ushort4*)(dst + (size_t)(d0 + d) * D_DIM + e0 + tx * 4) = o;
  }
}

extern "C" void kernel_launch(void* const* d_in, const int* in_sizes, int n_in,
                              void* d_out, int out_size, void* d_ws, size_t ws_size,
                              hipStream_t stream) {
  const float* x  = (const float*)d_in[0];
  const float* Wq = (const float*)d_in[1];
  const float* Wk = (const float*)d_in[2];
  const float* Wv = (const float*)d_in[3];
  const float* Wp = (const float*)d_in[4];
  const float* bp = (const float*)d_in[5];
  float* out = (float*)d_out;
  char* ws = (char*)d_ws;

  // Workspace layout (bytes); peak 197132288.
  // (Wpb,WqTb), (WvTb,WkTb), (P1,P2T) are consecutive 2 MB pairs so one
  // batched GEMM launch (z-stride DD) computes P1 and P2T.
  unsigned short* xb   = (unsigned short*)(ws + 0);          // 64 MB
  unsigned short* Wpb  = (unsigned short*)(ws + 67108864);   // 2 MB  (A, z=0)
  unsigned short* WqTb = (unsigned short*)(ws + 69206016);   // 2 MB  (A, z=1)
  unsigned short* WvTb = (unsigned short*)(ws + 71303168);   // 2 MB  (B, z=0)
  unsigned short* WkTb = (unsigned short*)(ws + 73400320);   // 2 MB  (B, z=1)
  unsigned short* P1   = (unsigned short*)(ws + 75497472);   // 2 MB  (C, z=0)
  unsigned short* P2T  = (unsigned short*)(ws + 77594624);   // 2 MB  (C, z=1)
  unsigned short* xT   = (unsigned short*)(ws + 79691776);   // 64 MB [B][D][S]
  unsigned short* G    = (unsigned short*)(ws + 146800640);  // 16 MB [B][1024][1024]
  unsigned short* T    = (unsigned short*)(ws + 163577856);  // 16 MB
  unsigned short* ET   = (unsigned short*)(ws + 180355072);  // 16 MB

  const long long DD = (long long)D_DIM * D_DIM;
  const long long SD = (long long)S_DIM * D_DIM;

  // ---- x: cast + transpose fused (read f32 once) ----
  dim3 gx(S_DIM / 64, D_DIM / 64, B_DIM);
  cast_transpose_x<<<gx, 256, 0, stream>>>(x, xb, xT);

  // ---- weights: Wq/Wk/Wv cast+transpose + Wp cast, one launch ----
  prep_w<<<dim3(16, 16, 4), 256, 0, stream>>>(Wq, Wk, Wv, Wp, WqTb, WkTb, WvTb, Wpb);

  // ---- P1 = Wp Wv, P2T = Wq^T Wk : one batched launch (z in {0,1}) ----
  dim3 gw(D_DIM / TILE_N, D_DIM / TILE_M, 2);        // (8,8,2)
  gemm_bt<false, false, false><<<gw, 256, 0, stream>>>(
      Wpb, WvTb, P1, D_DIM, D_DIM, D_DIM, D_DIM, DD, DD, DD, nullptr);

  // ---- G[b] = x_b^T x_b : upper-triangle 128-tiles (36); epilogue mirrors.
  gemm_bt<false, true, false><<<dim3(36, 1, B_DIM), 256, 0, stream>>>(
      xT, xT, G, S_DIM, S_DIM, S_DIM, D_DIM, SD, SD, DD, nullptr);

  // ---- T[b] = P1 G_b  (G symmetric): C[m,n] = sum_k P1[m,k] G[n,k].
  dim3 g1k(D_DIM / TILE_N, D_DIM / TILE_M, B_DIM);   // (8,8,8)
  gemm_bt<false, false, false><<<g1k, 256, 0, stream>>>(
      P1, G, T, D_DIM, D_DIM, D_DIM, D_DIM, 0, DD, DD, nullptr);

  // ---- ET[b] = T_b P2T^T + I : C[m,n] = sum_k T[m,k] P2T[n,k] + (m==n).
  gemm_bt<false, false, true><<<g1k, 256, 0, stream>>>(
      T, P2T, ET, D_DIM, D_DIM, D_DIM, D_DIM, DD, 0, DD, nullptr);

  // ---- out = x (E+I)^T ... = x ET^T + bp : per batch M=4096, fp32 out ----
  dim3 gf(D_DIM / TILE_N, S_DIM / TILE_M, B_DIM);    // (8,32,8)
  gemm_bt<true, false, false><<<gf, 256, 0, stream>>>(
      xb, ET, out, D_DIM, D_DIM, D_DIM, D_DIM, SD, DD, SD, bp);
  (void)in_sizes; (void)n_in; (void)out_size; (void)ws_size;
}